// Round 8
// baseline (352.286 us; speedup 1.0000x reference)
//
#include <hip/hip_runtime.h>
#include <hip/hip_bf16.h>

#define D_DIM 128
#define AST 136   // padded LDS row stride (shorts) for the A tile
#define CST 132   // padded LDS row stride (shorts) for the C transpose

typedef __attribute__((ext_vector_type(8))) short short8v;
typedef __attribute__((ext_vector_type(4))) short short4v;
typedef __attribute__((ext_vector_type(4))) float floatx4;

__device__ __forceinline__ short f2bf(float x) {
    unsigned u = __builtin_bit_cast(unsigned, x);
    unsigned r = u + 0x7fff + ((u >> 16) & 1);   // RNE
    return (short)(r >> 16);
}
__device__ __forceinline__ float bflo(unsigned p) {
    return __builtin_bit_cast(float, p << 16);
}
__device__ __forceinline__ float bfhi(unsigned p) {
    return __builtin_bit_cast(float, p & 0xffff0000u);
}
__device__ __forceinline__ float rdlanef(int v, int l) {
    return __builtin_bit_cast(float, __builtin_amdgcn_readlane(v, l));
}

// ---------------- build ----------------
// rec[v] = 16 ints = ONE 64B line: [0]=deg, [1..15]=src of edges 0..14.
// dinvA[v] = rsqrt(deg[v]+1)  (compact 400KB -> L2-resident for pack gathers)
// pk2[v*16+0] = {deg, f32 rsqrt(deg+1)}; pk2[v*16+1+j] = {src_j, dinv[src_j]}.

__global__ __launch_bounds__(256) void prep_kernel(int4* __restrict__ rec4, int nrec4,
                                                   const float* __restrict__ W,
                                                   short* __restrict__ Wt, int wt_total,
                                                   int* __restrict__ ovcnt) {
    int i = blockIdx.x * blockDim.x + threadIdx.x;
    if (i < nrec4) rec4[i] = make_int4(0, 0, 0, 0);
    if (i < wt_total) {
        int l = i >> 14;
        int r = i & 16383;
        int nn = r >> 7;
        int k  = r & 127;
        Wt[i] = f2bf(W[(size_t)l * 16384 + (size_t)k * 128 + nn]);
    }
    if (i == 0) *ovcnt = 0;
}

// single pass: atomic on rec[d][0] and slot write land in the SAME 64B line.
__global__ void fill2_kernel(const int* __restrict__ src, const int* __restrict__ dst,
                             int* __restrict__ rec,
                             int2* __restrict__ ov, int* __restrict__ ovcnt, int e) {
    int i = blockIdx.x * blockDim.x + threadIdx.x;
    if (i >= e) return;
    int s = src[i], d = dst[i];
    int j = atomicAdd(&rec[(size_t)d * 16], 1);
    if (j < 15) {
        rec[(size_t)d * 16 + 1 + j] = s;
    } else {
        int k = atomicAdd(ovcnt, 1);
        ov[k] = make_int2(d, s);
    }
}

__global__ __launch_bounds__(256) void dinv_kernel(const int* __restrict__ rec,
                                                   float* __restrict__ dinvA, int n) {
    int i = blockIdx.x * blockDim.x + threadIdx.x;
    if (i < n) dinvA[i] = rsqrtf((float)rec[(size_t)i * 16] + 1.0f);
}

// pack: rec -> pk2 with weights resolved from the COMPACT dinvA (400KB,
// L2-resident) instead of random 64B rec lines (R6's ~18us cost -> ~5us).
__global__ __launch_bounds__(256) void pack_kernel(const int* __restrict__ rec,
                                                   const float* __restrict__ dinvA,
                                                   int2* __restrict__ pk2, int n16) {
    int i = blockIdx.x * blockDim.x + threadIdx.x;
    if (i >= n16) return;
    const int lane = threadIdx.x & 63;
    const int val  = rec[i];
    const int j    = i & 15;
    const int degv = __shfl(val, lane & 48, 64);   // j==0 slot of this 16-group
    int2 out;
    if (j == 0) {
        out.x = val;
        out.y = __builtin_bit_cast(int, rsqrtf((float)val + 1.0f));
    } else {
        const int cap = degv < 15 ? degv : 15;
        float w = dinvA[val];                      // pads: val=0, safe
        if ((j - 1) >= cap) w = 0.0f;
        out.x = val;
        out.y = __builtin_bit_cast(int, w);
    }
    pk2[i] = out;
}

// ---------------- GEMM: H(bf16) = act @ W, A via LDS + B in VGPRs ----------------
template <bool IN_F32>
__global__ __launch_bounds__(256) void gemm_mfma_kernel(const void* __restrict__ Xv,
                                                        const short* __restrict__ Wt,
                                                        short* __restrict__ H, int n) {
    __shared__ short Alds[64 * AST];   // reused for the C transpose (64*CST fits)
    const int t    = threadIdx.x;
    const int wv   = t >> 6;
    const int lane = t & 63;
    const int m    = lane & 15;
    const int quad = lane >> 4;
    const int row0 = blockIdx.x * 64;

    short8v bfr[2][4];
    #pragma unroll
    for (int c = 0; c < 2; ++c) {
        const short* bp = Wt + (size_t)((wv * 2 + c) * 16 + m) * D_DIM + quad * 8;
        #pragma unroll
        for (int kt = 0; kt < 4; ++kt)
            bfr[c][kt] = *(const short8v*)(bp + kt * 32);
    }

    if constexpr (IN_F32) {
        const float* X = (const float*)Xv;
        #pragma unroll
        for (int i = 0; i < 8; ++i) {
            int q  = t + i * 256;
            int r  = q >> 5;
            int k4 = q & 31;
            int row = row0 + r;
            float4 v = make_float4(0.f, 0.f, 0.f, 0.f);
            if (row < n) v = *(const float4*)(X + (size_t)row * D_DIM + k4 * 4);
            short4v s;
            s.x = f2bf(v.x); s.y = f2bf(v.y); s.z = f2bf(v.z); s.w = f2bf(v.w);
            *(short4v*)(&Alds[r * AST + k4 * 4]) = s;
        }
    } else {
        const short* X = (const short*)Xv;
        #pragma unroll
        for (int i = 0; i < 4; ++i) {
            int q  = t + i * 256;
            int r  = q >> 4;
            int kc = q & 15;
            int row = row0 + r;
            short8v v = {0,0,0,0,0,0,0,0};
            if (row < n) v = *(const short8v*)(X + (size_t)row * D_DIM + kc * 8);
            *(short8v*)(&Alds[r * AST + kc * 8]) = v;
        }
    }
    __syncthreads();

    floatx4 acc[4][2];
    #pragma unroll
    for (int rt = 0; rt < 4; ++rt) {
        const short* ab = &Alds[(rt * 16 + m) * AST + quad * 8];
        short8v afr[4];
        #pragma unroll
        for (int kt = 0; kt < 4; ++kt) afr[kt] = *(const short8v*)(ab + kt * 32);
        #pragma unroll
        for (int c = 0; c < 2; ++c) {
            floatx4 a = (floatx4){0.f, 0.f, 0.f, 0.f};
            #pragma unroll
            for (int kt = 0; kt < 4; ++kt)
                a = __builtin_amdgcn_mfma_f32_16x16x32_bf16(afr[kt], bfr[c][kt], a, 0, 0, 0);
            acc[rt][c] = a;
        }
    }
    __syncthreads();   // all A reads done; reuse LDS for C

    #pragma unroll
    for (int rt = 0; rt < 4; ++rt) {
        #pragma unroll
        for (int c = 0; c < 2; ++c) {
            const int col = (wv * 2 + c) * 16 + m;
            #pragma unroll
            for (int r = 0; r < 4; ++r)
                Alds[(rt * 16 + quad * 4 + r) * CST + col] = f2bf(acc[rt][c][r]);
        }
    }
    __syncthreads();

    #pragma unroll
    for (int i = 0; i < 4; ++i) {
        int q  = t + i * 256;
        int r  = q >> 4;
        int kc = q & 15;
        int row = row0 + r;
        if (row < n)
            *(short8v*)(H + (size_t)row * D_DIM + kc * 8) = *(const short8v*)(&Alds[r * CST + kc * 8]);
    }
}

// ---------------- Aggregation + bias + ReLU + LayerNorm ----------------
// One wave per TWO consecutive nodes. ONE lane-distributed int2 load of pk2
// delivers deg, rsqrt(deg+1), and {src, weight} for 15 slots of BOTH nodes.
// Chain: pk2 load -> readlane -> gather -> FMA. Guarded chunks 7/4/4 keep the
// gather count near the true edge count; pad slots read row 0 (L2-hot) with
// weight 0. deg>15 tail via tiny overflow list.
template <bool OUT_BF16>
__global__ __launch_bounds__(256) void agg_kernel(const short* __restrict__ Hb,
                                                  const int2* __restrict__ pk2,
                                                  const float* __restrict__ dinvA,
                                                  const int2* __restrict__ ov,
                                                  const int* __restrict__ ovcnt,
                                                  const float* __restrict__ bias,
                                                  const float* __restrict__ gamma,
                                                  const float* __restrict__ beta,
                                                  void* __restrict__ Yv, int n) {
    const int wave = __builtin_amdgcn_readfirstlane(threadIdx.x >> 6);
    const int lane = threadIdx.x & 63;
    const int vA = (blockIdx.x * 4 + wave) * 2;
    if (vA >= n) return;
    const bool hasB = (vA + 1) < n;
    const int vB = hasB ? vA + 1 : vA;

    const int sl = lane & 31;
    const int2 mm = pk2[(size_t)vA * 16 + (hasB ? sl : (sl & 15))];
    const float2 bb = ((const float2*)bias)[lane];
    const float2 gg = ((const float2*)gamma)[lane];
    const float2 be = ((const float2*)beta)[lane];
    const unsigned psA = ((const unsigned*)(Hb + (size_t)vA * D_DIM))[lane];
    const unsigned psB = ((const unsigned*)(Hb + (size_t)vB * D_DIM))[lane];

    const int   cntA = __builtin_amdgcn_readlane(mm.x, 0);
    const float dvA  = rdlanef(mm.y, 0);
    const int   cntB = hasB ? __builtin_amdgcn_readlane(mm.x, 16) : 0;
    const float dvB  = hasB ? rdlanef(mm.y, 16) : dvA;

    // factored accumulation: out_pre = dv*(dv*h_self + sum_j dinv[s_j]*h_j)
    float axA = bflo(psA) * dvA;
    float ayA = bfhi(psA) * dvA;
    float axB = bflo(psB) * dvB;
    float ayB = bfhi(psB) * dvB;

    // ---- slots 0-6 (always; covers ~74% of nodes fully) ----
    {
        unsigned p[14]; float w[14];
        #pragma unroll
        for (int j = 0; j < 7; ++j) {
            const int sA = __builtin_amdgcn_readlane(mm.x, 1 + j);
            const int sB = __builtin_amdgcn_readlane(mm.x, 17 + j);
            p[j]     = ((const unsigned*)(Hb + (size_t)sA * D_DIM))[lane];
            p[7 + j] = ((const unsigned*)(Hb + (size_t)sB * D_DIM))[lane];
            w[j]     = rdlanef(mm.y, 1 + j);
            w[7 + j] = rdlanef(mm.y, 17 + j);
        }
        #pragma unroll
        for (int j = 0; j < 7; ++j) {
            axA = fmaf(w[j], bflo(p[j]), axA);
            ayA = fmaf(w[j], bfhi(p[j]), ayA);
            axB = fmaf(w[7 + j], bflo(p[7 + j]), axB);
            ayB = fmaf(w[7 + j], bfhi(p[7 + j]), ayB);
        }
    }
    // ---- slots 7-10 (~44% of pairs) ----
    if ((cntA > 7) | (cntB > 7)) {
        unsigned p[8]; float w[8];
        #pragma unroll
        for (int j = 0; j < 4; ++j) {
            const int sA = __builtin_amdgcn_readlane(mm.x, 8 + j);
            const int sB = __builtin_amdgcn_readlane(mm.x, 24 + j);
            p[j]     = ((const unsigned*)(Hb + (size_t)sA * D_DIM))[lane];
            p[4 + j] = ((const unsigned*)(Hb + (size_t)sB * D_DIM))[lane];
            w[j]     = rdlanef(mm.y, 8 + j);
            w[4 + j] = rdlanef(mm.y, 24 + j);
        }
        #pragma unroll
        for (int j = 0; j < 4; ++j) {
            axA = fmaf(w[j], bflo(p[j]), axA);
            ayA = fmaf(w[j], bfhi(p[j]), ayA);
            axB = fmaf(w[4 + j], bflo(p[4 + j]), axB);
            ayB = fmaf(w[4 + j], bfhi(p[4 + j]), ayB);
        }
        // ---- slots 11-14 (~4% of pairs) ----
        if ((cntA > 11) | (cntB > 11)) {
            #pragma unroll
            for (int j = 0; j < 4; ++j) {
                const int sA = __builtin_amdgcn_readlane(mm.x, 12 + j);
                const int sB = __builtin_amdgcn_readlane(mm.x, 28 + j);
                p[j]     = ((const unsigned*)(Hb + (size_t)sA * D_DIM))[lane];
                p[4 + j] = ((const unsigned*)(Hb + (size_t)sB * D_DIM))[lane];
                w[j]     = rdlanef(mm.y, 12 + j);
                w[4 + j] = rdlanef(mm.y, 28 + j);
            }
            #pragma unroll
            for (int j = 0; j < 4; ++j) {
                axA = fmaf(w[j], bflo(p[j]), axA);
                ayA = fmaf(w[j], bfhi(p[j]), ayA);
                axB = fmaf(w[4 + j], bflo(p[4 + j]), axB);
                ayB = fmaf(w[4 + j], bfhi(p[4 + j]), ayB);
            }
            // ---- deg>15 overflow (~0.1% of waves scan the tiny list) ----
            if ((cntA > 15) | (cntB > 15)) {
                const int oc = *ovcnt;
                for (int k = 0; k < oc; ++k) {
                    const int2 eo = ov[k];
                    if ((eo.x == vA) | (eo.x == vB)) {
                        const float ws = dinvA[eo.y];
                        const unsigned q = ((const unsigned*)(Hb + (size_t)eo.y * D_DIM))[lane];
                        if (eo.x == vA) {
                            axA = fmaf(ws, bflo(q), axA);
                            ayA = fmaf(ws, bfhi(q), ayA);
                        } else {
                            axB = fmaf(ws, bflo(q), axB);
                            ayB = fmaf(ws, bfhi(q), ayB);
                        }
                    }
                }
            }
        }
    }

    // --- bias + ReLU + LayerNorm epilogue ---
    #pragma unroll
    for (int s = 0; s < 2; ++s) {
        if (s == 1 && !hasB) break;
        const float dv = s ? dvB : dvA;
        float a0 = fmaxf(fmaf(dv, (s ? axB : axA), bb.x), 0.f);
        float a1 = fmaxf(fmaf(dv, (s ? ayB : ayA), bb.y), 0.f);
        float s1 = a0 + a1;
        float s2 = a0 * a0 + a1 * a1;
        #pragma unroll
        for (int mk = 1; mk < 64; mk <<= 1) {
            s1 += __shfl_xor(s1, mk, 64);
            s2 += __shfl_xor(s2, mk, 64);
        }
        const float mu  = s1 * (1.f / 128.f);
        const float var = s2 * (1.f / 128.f) - mu * mu;
        const float rs  = rsqrtf(var + 1e-5f);
        const float o0 = (a0 - mu) * rs * gg.x + be.x;
        const float o1 = (a1 - mu) * rs * gg.y + be.y;
        const int v = s ? vB : vA;
        if constexpr (OUT_BF16) {
            unsigned pack = (unsigned)(unsigned short)f2bf(o0) |
                            ((unsigned)(unsigned short)f2bf(o1) << 16);
            ((unsigned*)((short*)Yv + (size_t)v * D_DIM))[lane] = pack;
        } else {
            float2 o; o.x = o0; o.y = o1;
            ((float2*)((float*)Yv + (size_t)v * D_DIM))[lane] = o;
        }
    }
}

// ---------------- launch ----------------

extern "C" void kernel_launch(void* const* d_in, const int* in_sizes, int n_in,
                              void* d_out, int out_size, void* d_ws, size_t ws_size,
                              hipStream_t stream) {
    const float* x     = (const float*)d_in[0];
    const float* W     = (const float*)d_in[1];
    const float* bias  = (const float*)d_in[2];
    const float* gamma = (const float*)d_in[3];
    const float* beta  = (const float*)d_in[4];
    const int*   edges = (const int*)d_in[5];

    const int N = in_sizes[0] / D_DIM;
    const int E = in_sizes[5] / 2;
    const int L = in_sizes[1] / (D_DIM * D_DIM);

    const int* src = edges;
    const int* dst = edges + E;

    // workspace carve — 16B alignment maintained
    char* w = (char*)d_ws;
    short* Hb    = (short*)w; w += (size_t)N * D_DIM * sizeof(short);
    short* Act   = (short*)w; w += (size_t)N * D_DIM * sizeof(short);
    int*   rec   = (int*)w;   w += (size_t)N * 16 * sizeof(int);
    int2*  pk2   = (int2*)w;  w += (size_t)N * 16 * sizeof(int2);
    float* dinvA = (float*)w; w += (size_t)((N + 3) & ~3) * sizeof(float);
    int2*  ov    = (int2*)w;  w += (size_t)E * sizeof(int2);
    int*   ovcnt = (int*)w;   w += 16;
    short* Wt    = (short*)w; w += (size_t)L * D_DIM * D_DIM * sizeof(short);

    // build: prep -> fill2 -> dinv -> pack
    const int WT_TOTAL = L * D_DIM * D_DIM;
    const int NREC4 = N * 4;
    const int PREP_T = NREC4 > WT_TOTAL ? NREC4 : WT_TOTAL;
    prep_kernel<<<(PREP_T + 255) / 256, 256, 0, stream>>>((int4*)rec, NREC4, W, Wt,
                                                          WT_TOTAL, ovcnt);
    fill2_kernel<<<(E + 255) / 256, 256, 0, stream>>>(src, dst, rec, ov, ovcnt, E);
    dinv_kernel<<<(N + 255) / 256, 256, 0, stream>>>(rec, dinvA, N);
    pack_kernel<<<(N * 16 + 255) / 256, 256, 0, stream>>>(rec, dinvA, pk2, N * 16);

    const int GB = (N + 63) / 64;
    const int AB = (N + 7) / 8;   // 4 waves/block x 2 nodes/wave

    // layer 0: f32 x -> H(bf16) -> Act(bf16)
    gemm_mfma_kernel<true><<<GB, 256, 0, stream>>>(x, Wt, Hb, N);
    agg_kernel<true><<<AB, 256, 0, stream>>>(Hb, pk2, dinvA, ov, ovcnt,
                                             bias, gamma, beta, Act, N);
    // layers 1..L-2: bf16 -> bf16
    for (int l = 1; l < L - 1; ++l) {
        gemm_mfma_kernel<false><<<GB, 256, 0, stream>>>(Act, Wt + (size_t)l * D_DIM * D_DIM, Hb, N);
        agg_kernel<true><<<AB, 256, 0, stream>>>(Hb, pk2, dinvA, ov, ovcnt,
                                                 bias + (size_t)l * D_DIM,
                                                 gamma + (size_t)l * D_DIM,
                                                 beta + (size_t)l * D_DIM, Act, N);
    }
    // final layer: bf16 -> f32 d_out
    {
        int l = L - 1;
        gemm_mfma_kernel<false><<<GB, 256, 0, stream>>>(Act, Wt + (size_t)l * D_DIM * D_DIM, Hb, N);
        agg_kernel<false><<<AB, 256, 0, stream>>>(Hb, pk2, dinvA, ov, ovcnt,
                                                  bias + (size_t)l * D_DIM,
                                                  gamma + (size_t)l * D_DIM,
                                                  beta + (size_t)l * D_DIM, d_out, N);
    }
}

// Round 11
// 348.014 us; speedup vs baseline: 1.0123x; 1.0123x over previous
//
#include <hip/hip_runtime.h>
#include <hip/hip_bf16.h>

#define D_DIM 128
#define AST 136   // padded LDS row stride (shorts) for the A tile
#define CST 132   // padded LDS row stride (shorts) for the C transpose

typedef __attribute__((ext_vector_type(8))) short short8v;
typedef __attribute__((ext_vector_type(4))) short short4v;
typedef __attribute__((ext_vector_type(4))) float floatx4;

__device__ __forceinline__ short f2bf(float x) {
    unsigned u = __builtin_bit_cast(unsigned, x);
    unsigned r = u + 0x7fff + ((u >> 16) & 1);   // RNE
    return (short)(r >> 16);
}
__device__ __forceinline__ float bflo(unsigned p) {
    return __builtin_bit_cast(float, p << 16);
}
__device__ __forceinline__ float bfhi(unsigned p) {
    return __builtin_bit_cast(float, p & 0xffff0000u);
}

// ---------------- build (every kernel proven in R8) ----------------
// rec[v] = 16 ints = ONE 64B line: [0]=deg, [1..15]=src of edges 0..14
// (zero-init; pad slots read as src=0, weight forced 0 by cnt guard).
// dinvA[v] = rsqrt(deg[v]+1): compact 400KB, L2-resident -> scalar loads in agg.
// deg>15 overflow -> tiny ov list.

__global__ __launch_bounds__(256) void prep_kernel(int4* __restrict__ rec4, int nrec4,
                                                   const float* __restrict__ W,
                                                   short* __restrict__ Wt, int wt_total,
                                                   int* __restrict__ ovcnt) {
    int i = blockIdx.x * blockDim.x + threadIdx.x;
    if (i < nrec4) rec4[i] = make_int4(0, 0, 0, 0);
    if (i < wt_total) {
        int l = i >> 14;
        int r = i & 16383;
        int nn = r >> 7;
        int k  = r & 127;
        Wt[i] = f2bf(W[(size_t)l * 16384 + (size_t)k * 128 + nn]);
    }
    if (i == 0) *ovcnt = 0;
}

// single pass: atomic on rec[d][0] and slot write land in the SAME 64B line.
__global__ void fill2_kernel(const int* __restrict__ src, const int* __restrict__ dst,
                             int* __restrict__ rec,
                             int2* __restrict__ ov, int* __restrict__ ovcnt, int e) {
    int i = blockIdx.x * blockDim.x + threadIdx.x;
    if (i >= e) return;
    int s = src[i], d = dst[i];
    int j = atomicAdd(&rec[(size_t)d * 16], 1);
    if (j < 15) {
        rec[(size_t)d * 16 + 1 + j] = s;
    } else {
        int k = atomicAdd(ovcnt, 1);
        ov[k] = make_int2(d, s);
    }
}

__global__ __launch_bounds__(256) void dinv_kernel(const int* __restrict__ rec,
                                                   float* __restrict__ dinvA, int n) {
    int i = blockIdx.x * blockDim.x + threadIdx.x;
    if (i < n) dinvA[i] = rsqrtf((float)rec[(size_t)i * 16] + 1.0f);
}

// ---------------- GEMM: H(bf16) = act @ W (proven) ----------------
template <bool IN_F32>
__global__ __launch_bounds__(256) void gemm_mfma_kernel(const void* __restrict__ Xv,
                                                        const short* __restrict__ Wt,
                                                        short* __restrict__ H, int n) {
    __shared__ short Alds[64 * AST];
    const int t    = threadIdx.x;
    const int wv   = t >> 6;
    const int lane = t & 63;
    const int m    = lane & 15;
    const int quad = lane >> 4;
    const int row0 = blockIdx.x * 64;

    short8v bfr[2][4];
    #pragma unroll
    for (int c = 0; c < 2; ++c) {
        const short* bp = Wt + (size_t)((wv * 2 + c) * 16 + m) * D_DIM + quad * 8;
        #pragma unroll
        for (int kt = 0; kt < 4; ++kt)
            bfr[c][kt] = *(const short8v*)(bp + kt * 32);
    }

    if constexpr (IN_F32) {
        const float* X = (const float*)Xv;
        #pragma unroll
        for (int i = 0; i < 8; ++i) {
            int q  = t + i * 256;
            int r  = q >> 5;
            int k4 = q & 31;
            int row = row0 + r;
            float4 v = make_float4(0.f, 0.f, 0.f, 0.f);
            if (row < n) v = *(const float4*)(X + (size_t)row * D_DIM + k4 * 4);
            short4v s;
            s.x = f2bf(v.x); s.y = f2bf(v.y); s.z = f2bf(v.z); s.w = f2bf(v.w);
            *(short4v*)(&Alds[r * AST + k4 * 4]) = s;
        }
    } else {
        const short* X = (const short*)Xv;
        #pragma unroll
        for (int i = 0; i < 4; ++i) {
            int q  = t + i * 256;
            int r  = q >> 4;
            int kc = q & 15;
            int row = row0 + r;
            short8v v = {0,0,0,0,0,0,0,0};
            if (row < n) v = *(const short8v*)(X + (size_t)row * D_DIM + kc * 8);
            *(short8v*)(&Alds[r * AST + kc * 8]) = v;
        }
    }
    __syncthreads();

    floatx4 acc[4][2];
    #pragma unroll
    for (int rt = 0; rt < 4; ++rt) {
        const short* ab = &Alds[(rt * 16 + m) * AST + quad * 8];
        short8v afr[4];
        #pragma unroll
        for (int kt = 0; kt < 4; ++kt) afr[kt] = *(const short8v*)(ab + kt * 32);
        #pragma unroll
        for (int c = 0; c < 2; ++c) {
            floatx4 a = (floatx4){0.f, 0.f, 0.f, 0.f};
            #pragma unroll
            for (int kt = 0; kt < 4; ++kt)
                a = __builtin_amdgcn_mfma_f32_16x16x32_bf16(afr[kt], bfr[c][kt], a, 0, 0, 0);
            acc[rt][c] = a;
        }
    }
    __syncthreads();

    #pragma unroll
    for (int rt = 0; rt < 4; ++rt) {
        #pragma unroll
        for (int c = 0; c < 2; ++c) {
            const int col = (wv * 2 + c) * 16 + m;
            #pragma unroll
            for (int r = 0; r < 4; ++r)
                Alds[(rt * 16 + quad * 4 + r) * CST + col] = f2bf(acc[rt][c][r]);
        }
    }
    __syncthreads();

    #pragma unroll
    for (int i = 0; i < 4; ++i) {
        int q  = t + i * 256;
        int r  = q >> 4;
        int kc = q & 15;
        int row = row0 + r;
        if (row < n)
            *(short8v*)(H + (size_t)row * D_DIM + kc * 8) = *(const short8v*)(&Alds[r * CST + kc * 8]);
    }
}

// ---------------- Aggregation + bias + ReLU + LayerNorm ----------------
// Hybrid of proven parts: R6's rec indexing (ONE lane-distributed rec load:
// deg at readlane 0/16, srcs at 1..15/17..31; chunks 7/4/4; overflow >15)
// + R3's weight resolution (wave-uniform scalar loads dinvA[s] from the
// 400KB L2-resident array -> SMEM pipe, no per-lane gather, no pk2).
template <bool OUT_BF16>
__global__ __launch_bounds__(256) void agg_kernel(const short* __restrict__ Hb,
                                                  const int* __restrict__ rec,
                                                  const float* __restrict__ dinvA,
                                                  const int2* __restrict__ ov,
                                                  const int* __restrict__ ovcnt,
                                                  const float* __restrict__ bias,
                                                  const float* __restrict__ gamma,
                                                  const float* __restrict__ beta,
                                                  void* __restrict__ Yv, int n) {
    const int wave = __builtin_amdgcn_readfirstlane(threadIdx.x >> 6);
    const int lane = threadIdx.x & 63;
    const int vA = (blockIdx.x * 4 + wave) * 2;
    if (vA >= n) return;
    const bool hasB = (vA + 1) < n;
    const int vB = hasB ? vA + 1 : vA;

    // --- independent early loads ---
    const int sl = lane & 31;
    const int pk = rec[(size_t)vA * 16 + (hasB ? sl : (sl & 15))];
    const float2 bb = ((const float2*)bias)[lane];
    const float2 gg = ((const float2*)gamma)[lane];
    const float2 be = ((const float2*)beta)[lane];
    const unsigned psA = ((const unsigned*)(Hb + (size_t)vA * D_DIM))[lane];
    const unsigned psB = ((const unsigned*)(Hb + (size_t)vB * D_DIM))[lane];

    const int cntA = __builtin_amdgcn_readlane(pk, 0);
    const int cntB = hasB ? __builtin_amdgcn_readlane(pk, 16) : 0;
    const float dvA = rsqrtf((float)cntA + 1.0f);
    const float dvB = rsqrtf((float)cntB + 1.0f);
    const int capA = cntA < 15 ? cntA : 15;
    const int capB = cntB < 15 ? cntB : 15;

    // factored accumulation: out_pre = dv*(dv*h_self + sum_j dinv[s_j]*h_j)
    float axA = bflo(psA) * dvA;
    float ayA = bfhi(psA) * dvA;
    float axB = bflo(psB) * dvB;
    float ayB = bfhi(psB) * dvB;

    // ---- slots 0-6 (always; covers ~74% of nodes fully) ----
    {
        unsigned p[14]; float w[14];
        #pragma unroll
        for (int j = 0; j < 7; ++j) {
            const int sA = __builtin_amdgcn_readlane(pk, 1 + j);
            const int sB = __builtin_amdgcn_readlane(pk, 17 + j);
            p[j]     = ((const unsigned*)(Hb + (size_t)sA * D_DIM))[lane];
            p[7 + j] = ((const unsigned*)(Hb + (size_t)sB * D_DIM))[lane];
            w[j]     = (j < capA) ? dinvA[sA] : 0.f;
            w[7 + j] = (j < capB) ? dinvA[sB] : 0.f;
        }
        #pragma unroll
        for (int j = 0; j < 7; ++j) {
            axA = fmaf(w[j], bflo(p[j]), axA);
            ayA = fmaf(w[j], bfhi(p[j]), ayA);
            axB = fmaf(w[7 + j], bflo(p[7 + j]), axB);
            ayB = fmaf(w[7 + j], bfhi(p[7 + j]), ayB);
        }
    }
    // ---- slots 7-10 (~44% of pairs) ----
    if ((cntA > 7) | (cntB > 7)) {
        unsigned p[8]; float w[8];
        #pragma unroll
        for (int j = 0; j < 4; ++j) {
            const int sA = __builtin_amdgcn_readlane(pk, 8 + j);
            const int sB = __builtin_amdgcn_readlane(pk, 24 + j);
            p[j]     = ((const unsigned*)(Hb + (size_t)sA * D_DIM))[lane];
            p[4 + j] = ((const unsigned*)(Hb + (size_t)sB * D_DIM))[lane];
            w[j]     = (7 + j < capA) ? dinvA[sA] : 0.f;
            w[4 + j] = (7 + j < capB) ? dinvA[sB] : 0.f;
        }
        #pragma unroll
        for (int j = 0; j < 4; ++j) {
            axA = fmaf(w[j], bflo(p[j]), axA);
            ayA = fmaf(w[j], bfhi(p[j]), ayA);
            axB = fmaf(w[4 + j], bflo(p[4 + j]), axB);
            ayB = fmaf(w[4 + j], bfhi(p[4 + j]), ayB);
        }
        // ---- slots 11-14 (~4% of pairs) ----
        if ((cntA > 11) | (cntB > 11)) {
            #pragma unroll
            for (int j = 0; j < 4; ++j) {
                const int sA = __builtin_amdgcn_readlane(pk, 12 + j);
                const int sB = __builtin_amdgcn_readlane(pk, 28 + j);
                p[j]     = ((const unsigned*)(Hb + (size_t)sA * D_DIM))[lane];
                p[4 + j] = ((const unsigned*)(Hb + (size_t)sB * D_DIM))[lane];
                w[j]     = (11 + j < capA) ? dinvA[sA] : 0.f;
                w[4 + j] = (11 + j < capB) ? dinvA[sB] : 0.f;
            }
            #pragma unroll
            for (int j = 0; j < 4; ++j) {
                axA = fmaf(w[j], bflo(p[j]), axA);
                ayA = fmaf(w[j], bfhi(p[j]), ayA);
                axB = fmaf(w[4 + j], bflo(p[4 + j]), axB);
                ayB = fmaf(w[4 + j], bfhi(p[4 + j]), ayB);
            }
            // ---- deg>15 overflow (~0.1% of waves scan the tiny list) ----
            if ((cntA > 15) | (cntB > 15)) {
                const int oc = *ovcnt;
                for (int k = 0; k < oc; ++k) {
                    const int2 eo = ov[k];
                    if ((eo.x == vA) | (eo.x == vB)) {
                        const float ws = dinvA[eo.y];
                        const unsigned q = ((const unsigned*)(Hb + (size_t)eo.y * D_DIM))[lane];
                        if (eo.x == vA) {
                            axA = fmaf(ws, bflo(q), axA);
                            ayA = fmaf(ws, bfhi(q), ayA);
                        } else {
                            axB = fmaf(ws, bflo(q), axB);
                            ayB = fmaf(ws, bfhi(q), ayB);
                        }
                    }
                }
            }
        }
    }

    // --- bias + ReLU + LayerNorm epilogue (factored dv) ---
    #pragma unroll
    for (int s = 0; s < 2; ++s) {
        if (s == 1 && !hasB) break;
        const float dv = s ? dvB : dvA;
        float a0 = fmaxf(fmaf(dv, (s ? axB : axA), bb.x), 0.f);
        float a1 = fmaxf(fmaf(dv, (s ? ayB : ayA), bb.y), 0.f);
        float s1 = a0 + a1;
        float s2 = a0 * a0 + a1 * a1;
        #pragma unroll
        for (int mk = 1; mk < 64; mk <<= 1) {
            s1 += __shfl_xor(s1, mk, 64);
            s2 += __shfl_xor(s2, mk, 64);
        }
        const float mu  = s1 * (1.f / 128.f);
        const float var = s2 * (1.f / 128.f) - mu * mu;
        const float rs  = rsqrtf(var + 1e-5f);
        const float o0 = (a0 - mu) * rs * gg.x + be.x;
        const float o1 = (a1 - mu) * rs * gg.y + be.y;
        const int v = s ? vB : vA;
        if constexpr (OUT_BF16) {
            unsigned pack = (unsigned)(unsigned short)f2bf(o0) |
                            ((unsigned)(unsigned short)f2bf(o1) << 16);
            ((unsigned*)((short*)Yv + (size_t)v * D_DIM))[lane] = pack;
        } else {
            float2 o; o.x = o0; o.y = o1;
            ((float2*)((float*)Yv + (size_t)v * D_DIM))[lane] = o;
        }
    }
}

// ---------------- launch ----------------

extern "C" void kernel_launch(void* const* d_in, const int* in_sizes, int n_in,
                              void* d_out, int out_size, void* d_ws, size_t ws_size,
                              hipStream_t stream) {
    const float* x     = (const float*)d_in[0];
    const float* W     = (const float*)d_in[1];
    const float* bias  = (const float*)d_in[2];
    const float* gamma = (const float*)d_in[3];
    const float* beta  = (const float*)d_in[4];
    const int*   edges = (const int*)d_in[5];

    const int N = in_sizes[0] / D_DIM;
    const int E = in_sizes[5] / 2;
    const int L = in_sizes[1] / (D_DIM * D_DIM);

    const int* src = edges;
    const int* dst = edges + E;

    // workspace carve — 16B alignment maintained
    char* w = (char*)d_ws;
    short* Hb    = (short*)w; w += (size_t)N * D_DIM * sizeof(short);
    short* Act   = (short*)w; w += (size_t)N * D_DIM * sizeof(short);
    int*   rec   = (int*)w;   w += (size_t)N * 16 * sizeof(int);
    float* dinvA = (float*)w; w += (size_t)((N + 3) & ~3) * sizeof(float);
    int2*  ov    = (int2*)w;  w += (size_t)E * sizeof(int2);
    int*   ovcnt = (int*)w;   w += 16;
    short* Wt    = (short*)w; w += (size_t)L * D_DIM * D_DIM * sizeof(short);

    // build: prep (zero rec + Wt convert + ovcnt) -> fill2 -> dinv
    const int WT_TOTAL = L * D_DIM * D_DIM;
    const int NREC4 = N * 4;
    const int PREP_T = NREC4 > WT_TOTAL ? NREC4 : WT_TOTAL;
    prep_kernel<<<(PREP_T + 255) / 256, 256, 0, stream>>>((int4*)rec, NREC4, W, Wt,
                                                          WT_TOTAL, ovcnt);
    fill2_kernel<<<(E + 255) / 256, 256, 0, stream>>>(src, dst, rec, ov, ovcnt, E);
    dinv_kernel<<<(N + 255) / 256, 256, 0, stream>>>(rec, dinvA, N);

    const int GB = (N + 63) / 64;
    const int AB = (N + 7) / 8;   // 4 waves/block x 2 nodes/wave

    // layer 0: f32 x -> H(bf16) -> Act(bf16)
    gemm_mfma_kernel<true><<<GB, 256, 0, stream>>>(x, Wt, Hb, N);
    agg_kernel<true><<<AB, 256, 0, stream>>>(Hb, rec, dinvA, ov, ovcnt,
                                             bias, gamma, beta, Act, N);
    // layers 1..L-2: bf16 -> bf16
    for (int l = 1; l < L - 1; ++l) {
        gemm_mfma_kernel<false><<<GB, 256, 0, stream>>>(Act, Wt + (size_t)l * D_DIM * D_DIM, Hb, N);
        agg_kernel<true><<<AB, 256, 0, stream>>>(Hb, rec, dinvA, ov, ovcnt,
                                                 bias + (size_t)l * D_DIM,
                                                 gamma + (size_t)l * D_DIM,
                                                 beta + (size_t)l * D_DIM, Act, N);
    }
    // final layer: bf16 -> f32 d_out
    {
        int l = L - 1;
        gemm_mfma_kernel<false><<<GB, 256, 0, stream>>>(Act, Wt + (size_t)l * D_DIM * D_DIM, Hb, N);
        agg_kernel<false><<<AB, 256, 0, stream>>>(Hb, rec, dinvA, ov, ovcnt,
                                                  bias + (size_t)l * D_DIM,
                                                  gamma + (size_t)l * D_DIM,
                                                  beta + (size_t)l * D_DIM, d_out, N);
    }
}